// Round 18
// baseline (210.043 us; speedup 1.0000x reference)
//
#include <hip/hip_runtime.h>
#include <hip/hip_bf16.h>

#define NNODES 100000
#define NEDGES 1600000
#define NF 256
#define NH 128
#define SCAN_ELEMS 1024
#define SCAN_NBLK ((NNODES + SCAN_ELEMS - 1) / SCAN_ELEMS)   // 98

// LDS-privatized histogram / fill parameters
#define HG 200                     // chunks
#define HCHUNK (NEDGES / HG)       // 8000 edges per chunk
#define HBINS 50000                // nodes per pass (100 KB LDS)
#define HR 2                       // passes
#define HWORDS (NNODES / 2)        // packed words per partial slice

#define WPREP_BLOCKS 129           // (NF*NH + NH + 255)/256

typedef _Float16 half4v __attribute__((ext_vector_type(4)));
typedef _Float16 half8v __attribute__((ext_vector_type(8)));
typedef float floatx16 __attribute__((ext_vector_type(16)));

// k-permutation within each 16-block so MFMA f16 fragments (k = g*4 + (j&3) + 8*(j>>2))
// are 8 contiguous halves in storage. perm: [0,1,2,3, 8,9,10,11, 4,5,6,7, 12,13,14,15]
__device__ __forceinline__ int pos16(int k) {        // logical k (0..15) -> storage pos
    return (((k >> 2) & 1) << 3) + (k & 3) + (((k >> 3) & 1) << 2);
}
__device__ __forceinline__ int ipos16(int p) {       // storage pos -> logical k
    int g = (p >> 3) & 1, j = p & 7;
    return g * 4 + (j & 3) + ((j >> 2) << 3);
}

__device__ __forceinline__ float2 h2f2(unsigned u) {
    union { unsigned u; _Float16 h[2]; } c; c.u = u;
    return make_float2((float)c.h[0], (float)c.h[1]);
}

// async global->LDS DMA, 16 B per lane; LDS dest = wave base + lane*16 (linear)
__device__ __forceinline__ void load_lds16(const void* g, void* l) {
    __builtin_amdgcn_global_load_lds(
        (const __attribute__((address_space(1))) void*)g,
        (__attribute__((address_space(3))) void*)l, 16, 0, 0);
}

// ---------------- LDS-privatized degree histogram (2 passes) ----------------
// Also records each edge's intra-chunk in-degree rank (byte) for the fill pass.
__global__ __launch_bounds__(512)
void hist_part_kernel(const int* __restrict__ src, const int* __restrict__ dst,
                      unsigned* __restrict__ partial, unsigned char* __restrict__ rank8) {
    __shared__ unsigned lds[HBINS / 2];        // 25000 words = 100 KB
    const int g = blockIdx.x, t = threadIdx.x;
    const int e0 = g * HCHUNK;
    for (int r = 0; r < HR; ++r) {
        const int lo = r * HBINS;
        for (int i = t; i < HBINS / 2; i += 512) lds[i] = 0;
        __syncthreads();
        for (int i = t; i < HCHUNK; i += 512) {
            unsigned us = (unsigned)(src[e0 + i] - lo);
            if (us < HBINS) atomicAdd(&lds[us >> 1], 1u << ((us & 1) * 16));
            unsigned ud = (unsigned)(dst[e0 + i] - lo);
            if (ud < HBINS) {
                unsigned sh = (ud & 1) * 16 + 8;
                unsigned prev = atomicAdd(&lds[ud >> 1], 1u << sh);
                rank8[e0 + i] = (unsigned char)((prev >> sh) & 0xffu);
            }
        }
        __syncthreads();
        unsigned* dp = partial + (size_t)g * HWORDS + (lo >> 1);
        for (int i = t; i < HBINS / 2; i += 512) dp[i] = lds[i];
        __syncthreads();
    }
}

// ---------------- fused: per-chunk exclusive scan + degree reduce + norms ----
__global__ __launch_bounds__(256)
void degscan_kernel(const unsigned* __restrict__ partial,
                    unsigned char* __restrict__ offb,
                    float* __restrict__ ns, float* __restrict__ nd,
                    int* __restrict__ cnt_in) {
    int w = blockIdx.x * 256 + threadIdx.x;
    if (w >= HWORDS) return;
    unsigned o0 = 0, i0 = 0, o1 = 0, i1 = 0;
    for (int g0 = 0; g0 < HG; g0 += 8) {
        unsigned v[8];
        #pragma unroll
        for (int j = 0; j < 8; ++j) v[j] = partial[(size_t)(g0 + j) * HWORDS + w];
        #pragma unroll
        for (int j = 0; j < 8; ++j) {
            *(unsigned short*)(offb + (size_t)(g0 + j) * NNODES + 2 * w) =
                (unsigned short)((i0 & 0xffu) | ((i1 & 0xffu) << 8));
            o0 += v[j] & 0xffu;         i0 += (v[j] >> 8) & 0xffu;
            o1 += (v[j] >> 16) & 0xffu; i1 += v[j] >> 24;
        }
    }
    int n0 = 2 * w, n1 = 2 * w + 1;
    ns[n0] = rsqrtf((float)max((int)o0, 1));
    nd[n0] = rsqrtf((float)max((int)i0, 1));
    cnt_in[n0] = (int)i0;
    ns[n1] = rsqrtf((float)max((int)o1, 1));
    nd[n1] = rsqrtf((float)max((int)i1, 1));
    cnt_in[n1] = (int)i1;
}

// ---------------- 3-pass exclusive scan over cnt_in -> row_ptr --------------
__global__ __launch_bounds__(256)
void scanA_kernel(const int* __restrict__ cnt, int* __restrict__ pre,
                  int* __restrict__ bsum, int n) {
    __shared__ int tsum[256];
    int b = blockIdx.x, t = threadIdx.x;
    int base = b * SCAN_ELEMS + t * 4;
    int v[4]; int s = 0;
    #pragma unroll
    for (int k = 0; k < 4; ++k) { int idx = base + k; v[k] = (idx < n) ? cnt[idx] : 0; s += v[k]; }
    tsum[t] = s;
    __syncthreads();
    for (int off = 1; off < 256; off <<= 1) {
        int val = (t >= off) ? tsum[t - off] : 0;
        __syncthreads();
        tsum[t] += val;
        __syncthreads();
    }
    int run = (t == 0) ? 0 : tsum[t - 1];
    #pragma unroll
    for (int k = 0; k < 4; ++k) { int idx = base + k; if (idx < n) pre[idx] = run; run += v[k]; }
    if (t == 255) bsum[b] = tsum[255];
}

__global__ __launch_bounds__(128)
void scanB_kernel(int* __restrict__ bsum, int nb, int* __restrict__ row_ptr) {
    __shared__ int s[128];
    int t = threadIdx.x;
    int v = (t < nb) ? bsum[t] : 0;
    s[t] = v;
    __syncthreads();
    for (int off = 1; off < 128; off <<= 1) {
        int u = (t >= off) ? s[t - off] : 0;
        __syncthreads();
        s[t] += u;
        __syncthreads();
    }
    if (t < nb) bsum[t] = s[t] - v;           // exclusive block sums
    if (t == 0) row_ptr[NNODES] = NEDGES;
}

__global__ __launch_bounds__(256)
void scanC_kernel(int* __restrict__ pre, const int* __restrict__ bsum, int n) {
    int add = bsum[blockIdx.x];
    int base = blockIdx.x * SCAN_ELEMS + threadIdx.x;
    #pragma unroll
    for (int k = 0; k < 4; ++k) {
        int idx = base + k * 256;
        if (idx < n) pre[idx] += add;
    }
}

// ---------------- single-pass atomic-free fill using stored ranks -----------
__global__ __launch_bounds__(256)
void fill_kernel(const int* __restrict__ src, const int* __restrict__ dst,
                 const unsigned char* __restrict__ rank8,
                 const int* __restrict__ row_ptr, const unsigned char* __restrict__ offb,
                 int* __restrict__ col, int E) {
    int e = blockIdx.x * 256 + threadIdx.x;
    if (e >= E) return;
    int d = dst[e];
    int g = e / HCHUNK;
    int pos = row_ptr[d] + (int)offb[(size_t)g * NNODES + d] + (int)rank8[e];
    col[pos] = src[e];
}

// ---------------- weight prep: W1 transpose+perm, b1 perm, v2 = W2@Wfc, c0 --
__global__ __launch_bounds__(256)
void prep_w_kernel(const float* __restrict__ W1, const float* __restrict__ b1,
                   _Float16* __restrict__ Wt1, float* __restrict__ b1p,
                   const float* __restrict__ W2, const float* __restrict__ Wfc,
                   const float* __restrict__ b2, const float* __restrict__ bfc,
                   float* __restrict__ v2p, float* __restrict__ c0) {
    int b = blockIdx.x, t = threadIdx.x;
    if (b < WPREP_BLOCKS) {
        int id = b * 256 + t;
        if (id < NF * NH) {                    // W1 -> Wt1[n][perm(k)] f16
            int k = id >> 7, n = id & 127;
            Wt1[(size_t)n * NF + (k & ~15) + pos16(k & 15)] = (_Float16)W1[id];
        } else if (id < NF * NH + NH) {
            int pos = id - NF * NH;
            int k = (pos & ~15) + ipos16(pos & 15);
            b1p[pos] = b1[k];
        }
    } else {
        // v2 = W2 @ Wfc (perm order), c0 = b2.Wfc + bfc
        if (t < 128) {
            float s = 0.f;
            #pragma unroll 16
            for (int j = 0; j < 128; ++j) s += W2[t * 128 + j] * Wfc[j];
            v2p[(t & ~15) + pos16(t & 15)] = s;
        } else if (t < 192) {
            int lane = t - 128;
            float c = b2[lane] * Wfc[lane] + b2[lane + 64] * Wfc[lane + 64];
            #pragma unroll
            for (int off = 32; off > 0; off >>= 1) c += __shfl_down(c, off);
            if (lane == 0) c0[0] = c + bfc[0];
        }
    }
}

// ---------------- fused GEMM1: C = (x @ W1) * ns, barrier-free per-wave -----
// One 32-row tile per wave, 4 waves/block, wave-private 2x4KB LDS dbuf ->
// ZERO barriers (vmcnt is per-wave). 16 fully independent wave-streams/CU
// cover the ~2000-cycle loaded DMA latency. Counted vmcnt(4): next slab's
// DMAs stay in flight while computing current. Rows clamped (uniform DMA
// count per wave). XOR chunk-swizzle on global source + matching ds_read.
__global__ __launch_bounds__(256, 4)
void gemm1_kernel(const float* __restrict__ X, const _Float16* __restrict__ Wt,
                  const float* __restrict__ norm_s, _Float16* __restrict__ Cout,
                  int N) {
    __shared__ __align__(16) float As[4][2][32 * 32];   // per-wave dbuf (4 x 8 KB)
    const int tid = threadIdx.x;
    const int l = tid & 63, w = tid >> 6;
    const int row0 = (blockIdx.x * 4 + w) * 32;
    if (row0 >= N) return;                     // safe: no barriers in this kernel

    const int ar = l & 31;
    const int swz = ar & 7;
    const int g = l >> 5;
    const int lr = l >> 3, lc = l & 7;         // staging: 8 rows/DMA, 8 chunks/row
    float* buf0 = &As[w][0][0];
    float* buf1 = &As[w][1][0];
    floatx16 acc[4] = {};

    // prologue: slab 0 -> buf0 (4 DMAs, rows clamped)
    #pragma unroll
    for (int i = 0; i < 4; ++i) {
        int r = i * 8 + lr;
        int grow = min(row0 + r, N - 1);
        int srcc = lc ^ (r & 7);
        load_lds16(X + (size_t)grow * NF + srcc * 4, buf0 + i * 256);
    }

    for (int t = 0; t < 8; ++t) {
        float* cur = (t & 1) ? buf1 : buf0;
        float* nxt = (t & 1) ? buf0 : buf1;
        if (t < 7) {
            #pragma unroll
            for (int i = 0; i < 4; ++i) {
                int r = i * 8 + lr;
                int grow = min(row0 + r, N - 1);
                int srcc = lc ^ (r & 7);
                load_lds16(X + (size_t)grow * NF + (t + 1) * 32 + srcc * 4, nxt + i * 256);
            }
            __builtin_amdgcn_sched_barrier(0);
            asm volatile("s_waitcnt vmcnt(4)" ::: "memory");   // slab t ready; t+1 in flight
            __builtin_amdgcn_sched_barrier(0);
        } else {
            __builtin_amdgcn_sched_barrier(0);
            asm volatile("s_waitcnt vmcnt(0)" ::: "memory");
            __builtin_amdgcn_sched_barrier(0);
        }
        #pragma unroll
        for (int kk = 0; kk < 2; ++kk) {
            int ca = kk * 4 + g;               // chunk with k = 16kk+4g+0..3
            int cb = ca + 2;                   // chunk with k = 16kk+4g+8..11
            float4 al = *(const float4*)(cur + ar * 32 + (ca ^ swz) * 4);
            float4 ah = *(const float4*)(cur + ar * 32 + (cb ^ swz) * 4);
            half8v a0 = { (_Float16)al.x, (_Float16)al.y, (_Float16)al.z, (_Float16)al.w,
                          (_Float16)ah.x, (_Float16)ah.y, (_Float16)ah.z, (_Float16)ah.w };
            const _Float16* bp = Wt + (size_t)ar * NF + g * 8 + (t * 2 + kk) * 16;
            #pragma unroll
            for (int n = 0; n < 4; ++n) {
                half8v b = *(const half8v*)(bp + (size_t)n * 32 * NF);
                acc[n] = __builtin_amdgcn_mfma_f32_32x32x16_f16(a0, b, acc[n], 0, 0, 0);
            }
        }
    }

    // epilogue: D row = (r&3)+8*(r>>2)+4*(l>>5), col = l&31; scale by ns[row]
    const int cpos = pos16(l & 15);
    const int chi = ((l >> 4) & 1) << 4;
    #pragma unroll
    for (int r = 0; r < 16; ++r) {
        int rloc = (r & 3) + ((r >> 2) << 3) + ((l >> 5) << 2);
        int grow = row0 + rloc;
        if (grow < N) {
            float s = norm_s[grow];
            _Float16* crow = Cout + (size_t)grow * NH + chi + cpos;
            #pragma unroll
            for (int n = 0; n < 4; ++n)
                crow[n * 32] = (_Float16)(acc[n][r] * s);
        }
    }
}

// ---------------- fused gather + layer-1 epilogue + z-dot, one wave/node ----
__global__ __launch_bounds__(512)
void gatherz_kernel(const _Float16* __restrict__ m, const int* __restrict__ row_ptr,
                    const int* __restrict__ col, const float* __restrict__ norm_d,
                    const float* __restrict__ norm_s, const float* __restrict__ b1p,
                    const float* __restrict__ v2p, float* __restrict__ z, int N) {
    int w = (blockIdx.x * 512 + threadIdx.x) >> 6;
    int lane = threadIdx.x & 63;
    if (w >= N) return;
    int beg = __builtin_amdgcn_readfirstlane(row_ptr[w]);
    int end = __builtin_amdgcn_readfirstlane(row_ptr[w + 1]);
    const unsigned* mu = (const unsigned*)m + lane;  // lane's column slot
    float ax = 0.f, ay = 0.f;
    int i = beg;
    for (; i + 15 < end; i += 16) {
        unsigned u[16];
        #pragma unroll
        for (int j = 0; j < 16; ++j) u[j] = mu[(size_t)col[i + j] * 64];
        #pragma unroll
        for (int j = 0; j < 16; ++j) { float2 v = h2f2(u[j]); ax += v.x; ay += v.y; }
    }
    for (; i + 3 < end; i += 4) {
        unsigned u[4];
        #pragma unroll
        for (int j = 0; j < 4; ++j) u[j] = mu[(size_t)col[i + j] * 64];
        #pragma unroll
        for (int j = 0; j < 4; ++j) { float2 v = h2f2(u[j]); ax += v.x; ay += v.y; }
    }
    for (; i < end; ++i) {
        float2 v = h2f2(mu[(size_t)col[i] * 64]);
        ax += v.x; ay += v.y;
    }
    float nd = norm_d[w], ns = norm_s[w];
    float2 bv = ((const float2*)b1p)[lane];
    float hx = fmaxf(fmaf(ax, nd, bv.x), 0.f) * ns;
    float hy = fmaxf(fmaf(ay, nd, bv.y), 0.f) * ns;
    float2 w2 = ((const float2*)v2p)[lane];
    float p = fmaf(hx, w2.x, hy * w2.y);
    #pragma unroll
    for (int off = 32; off > 0; off >>= 1) p += __shfl_down(p, off);
    if (lane == 0) z[w] = p;
}

// ---------------- scalar CSR sum: out[w] = nd*sum z[col] + c0 ---------------
__global__ __launch_bounds__(256)
void outsum_kernel(const float* __restrict__ z, const int* __restrict__ row_ptr,
                   const int* __restrict__ col, const float* __restrict__ norm_d,
                   const float* __restrict__ c0, float* __restrict__ out, int N) {
    int w = blockIdx.x * 256 + threadIdx.x;
    if (w >= N) return;
    int beg = row_ptr[w], end = row_ptr[w + 1];
    float s0 = 0.f, s1 = 0.f, s2 = 0.f, s3 = 0.f;
    int i = beg;
    for (; i + 3 < end; i += 4) {
        s0 += z[col[i]];     s1 += z[col[i + 1]];
        s2 += z[col[i + 2]]; s3 += z[col[i + 3]];
    }
    for (; i < end; ++i) s0 += z[col[i]];
    out[w] = norm_d[w] * ((s0 + s1) + (s2 + s3)) + c0[0];
}

extern "C" void kernel_launch(void* const* d_in, const int* in_sizes, int n_in,
                              void* d_out, int out_size, void* d_ws, size_t ws_size,
                              hipStream_t stream) {
    const float* x   = (const float*)d_in[0];
    const float* W1  = (const float*)d_in[1];
    const float* b1  = (const float*)d_in[2];
    const float* W2  = (const float*)d_in[3];
    const float* b2  = (const float*)d_in[4];
    const float* Wfc = (const float*)d_in[5];
    const float* bfc = (const float*)d_in[6];
    const int*   src = (const int*)d_in[7];
    const int*   dst = (const int*)d_in[8];
    float* out = (float*)d_out;

    const int N = NNODES, E = NEDGES;

    // workspace layout (all offsets 16B-aligned)
    char* p = (char*)d_ws;
    float*    norm_s = (float*)p;      p += (size_t)N * 4;
    float*    norm_d = (float*)p;      p += (size_t)N * 4;
    _Float16* bufA_h = (_Float16*)p;   p += (size_t)N * NH * 2;   // m1 (25.6 MB)
    _Float16* Wt1    = (_Float16*)p;   p += (size_t)NF * NH * 2;
    float*    b1p    = (float*)p;      p += NH * 4;
    float*    v2p    = (float*)p;      p += NH * 4;
    float*    c0     = (float*)p;      p += 16;
    float*    z      = (float*)p;      p += (size_t)N * 4;
    int*      cnt_in = (int*)p;        p += (size_t)N * 4;
    int*      row_ptr= (int*)p;        p += (size_t)(N + 1) * 4 + 12;  // keep 16B align
    int*      col    = (int*)p;        p += (size_t)E * 4;
    int*      bsum   = (int*)p;        p += 128 * 4;
    unsigned char* rank8 = (unsigned char*)p;  p += (size_t)E;    // 1.6 MB
    unsigned* partial= (unsigned*)p;   // HG * HWORDS * 4 = 40 MB
    // offb (20 MB) aliases bufA_h (25.6 MB): dead before gemm1 writes bufA_h.
    unsigned char* offb = (unsigned char*)bufA_h;

    // ---- CSR build + norms + weight prep (zero global atomics) ----
    hist_part_kernel<<<HG, 512, 0, stream>>>(src, dst, partial, rank8);
    degscan_kernel<<<(HWORDS + 255) / 256, 256, 0, stream>>>(partial, offb, norm_s, norm_d, cnt_in);
    scanA_kernel<<<SCAN_NBLK, 256, 0, stream>>>(cnt_in, row_ptr, bsum, N);
    scanB_kernel<<<1, 128, 0, stream>>>(bsum, SCAN_NBLK, row_ptr);
    scanC_kernel<<<SCAN_NBLK, 256, 0, stream>>>(row_ptr, bsum, N);
    fill_kernel<<<(E + 255) / 256, 256, 0, stream>>>(src, dst, rank8, row_ptr, offb, col, E);
    prep_w_kernel<<<WPREP_BLOCKS + 1, 256, 0, stream>>>(W1, b1, Wt1, b1p,
                                                        W2, Wfc, b2, bfc, v2p, c0);

    // ---- layer 1 GEMM (convx fused, barrier-free waves): m1 = (x @ W1) * ns ----
    gemm1_kernel<<<(N + 127) / 128, 256, 0, stream>>>(x, Wt1, norm_s, bufA_h, N);
    // ---- fused: agg1 -> h -> z (layer 2 collapsed into v2 dot) ----
    gatherz_kernel<<<((size_t)N * 64 + 511) / 512, 512, 0, stream>>>(
        bufA_h, row_ptr, col, norm_d, norm_s, b1p, v2p, z, N);
    // ---- out[w] = nd * sum z[col] + c0 ----
    outsum_kernel<<<(N + 255) / 256, 256, 0, stream>>>(z, row_ptr, col, norm_d, c0, out, N);
}

// Round 19
// 195.885 us; speedup vs baseline: 1.0723x; 1.0723x over previous
//
#include <hip/hip_runtime.h>
#include <hip/hip_bf16.h>

#define NNODES 100000
#define NEDGES 1600000
#define NF 256
#define NH 128
#define SCAN_ELEMS 1024
#define SCAN_NBLK ((NNODES + SCAN_ELEMS - 1) / SCAN_ELEMS)   // 98

// LDS-privatized histogram / fill parameters
#define HG 200                     // chunks
#define HCHUNK (NEDGES / HG)       // 8000 edges per chunk
#define HBINS 50000                // nodes per pass (100 KB LDS)
#define HR 2                       // passes
#define HWORDS (NNODES / 2)        // packed words per partial slice

#define WPREP_BLOCKS 129           // (NF*NH + NH + 255)/256

typedef _Float16 half4v __attribute__((ext_vector_type(4)));
typedef _Float16 half8v __attribute__((ext_vector_type(8)));
typedef float floatx16 __attribute__((ext_vector_type(16)));

// k-permutation within each 16-block so MFMA f16 fragments (k = g*4 + (j&3) + 8*(j>>2))
// are 8 contiguous halves in storage. perm: [0,1,2,3, 8,9,10,11, 4,5,6,7, 12,13,14,15]
__device__ __forceinline__ int pos16(int k) {        // logical k (0..15) -> storage pos
    return (((k >> 2) & 1) << 3) + (k & 3) + (((k >> 3) & 1) << 2);
}
__device__ __forceinline__ int ipos16(int p) {       // storage pos -> logical k
    int g = (p >> 3) & 1, j = p & 7;
    return g * 4 + (j & 3) + ((j >> 2) << 3);
}

__device__ __forceinline__ float2 h2f2(unsigned u) {
    union { unsigned u; _Float16 h[2]; } c; c.u = u;
    return make_float2((float)c.h[0], (float)c.h[1]);
}

// async global->LDS DMA, 16 B per lane; LDS dest = wave base + lane*16 (linear)
__device__ __forceinline__ void load_lds16(const void* g, void* l) {
    __builtin_amdgcn_global_load_lds(
        (const __attribute__((address_space(1))) void*)g,
        (__attribute__((address_space(3))) void*)l, 16, 0, 0);
}

// ---------------- LDS-privatized degree histogram (2 passes) ----------------
// Also records each edge's intra-chunk in-degree rank (byte) for the fill pass.
__global__ __launch_bounds__(512)
void hist_part_kernel(const int* __restrict__ src, const int* __restrict__ dst,
                      unsigned* __restrict__ partial, unsigned char* __restrict__ rank8) {
    __shared__ unsigned lds[HBINS / 2];        // 25000 words = 100 KB
    const int g = blockIdx.x, t = threadIdx.x;
    const int e0 = g * HCHUNK;
    for (int r = 0; r < HR; ++r) {
        const int lo = r * HBINS;
        for (int i = t; i < HBINS / 2; i += 512) lds[i] = 0;
        __syncthreads();
        for (int i = t; i < HCHUNK; i += 512) {
            unsigned us = (unsigned)(src[e0 + i] - lo);
            if (us < HBINS) atomicAdd(&lds[us >> 1], 1u << ((us & 1) * 16));
            unsigned ud = (unsigned)(dst[e0 + i] - lo);
            if (ud < HBINS) {
                unsigned sh = (ud & 1) * 16 + 8;
                unsigned prev = atomicAdd(&lds[ud >> 1], 1u << sh);
                rank8[e0 + i] = (unsigned char)((prev >> sh) & 0xffu);
            }
        }
        __syncthreads();
        unsigned* dp = partial + (size_t)g * HWORDS + (lo >> 1);
        for (int i = t; i < HBINS / 2; i += 512) dp[i] = lds[i];
        __syncthreads();
    }
}

// ---------------- fused: per-chunk exclusive scan + degree reduce + norms ----
__global__ __launch_bounds__(256)
void degscan_kernel(const unsigned* __restrict__ partial,
                    unsigned char* __restrict__ offb,
                    float* __restrict__ ns, float* __restrict__ nd,
                    int* __restrict__ cnt_in) {
    int w = blockIdx.x * 256 + threadIdx.x;
    if (w >= HWORDS) return;
    unsigned o0 = 0, i0 = 0, o1 = 0, i1 = 0;
    for (int g0 = 0; g0 < HG; g0 += 8) {
        unsigned v[8];
        #pragma unroll
        for (int j = 0; j < 8; ++j) v[j] = partial[(size_t)(g0 + j) * HWORDS + w];
        #pragma unroll
        for (int j = 0; j < 8; ++j) {
            *(unsigned short*)(offb + (size_t)(g0 + j) * NNODES + 2 * w) =
                (unsigned short)((i0 & 0xffu) | ((i1 & 0xffu) << 8));
            o0 += v[j] & 0xffu;         i0 += (v[j] >> 8) & 0xffu;
            o1 += (v[j] >> 16) & 0xffu; i1 += v[j] >> 24;
        }
    }
    int n0 = 2 * w, n1 = 2 * w + 1;
    ns[n0] = rsqrtf((float)max((int)o0, 1));
    nd[n0] = rsqrtf((float)max((int)i0, 1));
    cnt_in[n0] = (int)i0;
    ns[n1] = rsqrtf((float)max((int)o1, 1));
    nd[n1] = rsqrtf((float)max((int)i1, 1));
    cnt_in[n1] = (int)i1;
}

// ---------------- 3-pass exclusive scan over cnt_in -> row_ptr --------------
__global__ __launch_bounds__(256)
void scanA_kernel(const int* __restrict__ cnt, int* __restrict__ pre,
                  int* __restrict__ bsum, int n) {
    __shared__ int tsum[256];
    int b = blockIdx.x, t = threadIdx.x;
    int base = b * SCAN_ELEMS + t * 4;
    int v[4]; int s = 0;
    #pragma unroll
    for (int k = 0; k < 4; ++k) { int idx = base + k; v[k] = (idx < n) ? cnt[idx] : 0; s += v[k]; }
    tsum[t] = s;
    __syncthreads();
    for (int off = 1; off < 256; off <<= 1) {
        int val = (t >= off) ? tsum[t - off] : 0;
        __syncthreads();
        tsum[t] += val;
        __syncthreads();
    }
    int run = (t == 0) ? 0 : tsum[t - 1];
    #pragma unroll
    for (int k = 0; k < 4; ++k) { int idx = base + k; if (idx < n) pre[idx] = run; run += v[k]; }
    if (t == 255) bsum[b] = tsum[255];
}

__global__ __launch_bounds__(128)
void scanB_kernel(int* __restrict__ bsum, int nb, int* __restrict__ row_ptr) {
    __shared__ int s[128];
    int t = threadIdx.x;
    int v = (t < nb) ? bsum[t] : 0;
    s[t] = v;
    __syncthreads();
    for (int off = 1; off < 128; off <<= 1) {
        int u = (t >= off) ? s[t - off] : 0;
        __syncthreads();
        s[t] += u;
        __syncthreads();
    }
    if (t < nb) bsum[t] = s[t] - v;           // exclusive block sums
    if (t == 0) row_ptr[NNODES] = NEDGES;
}

__global__ __launch_bounds__(256)
void scanC_kernel(int* __restrict__ pre, const int* __restrict__ bsum, int n) {
    int add = bsum[blockIdx.x];
    int base = blockIdx.x * SCAN_ELEMS + threadIdx.x;
    #pragma unroll
    for (int k = 0; k < 4; ++k) {
        int idx = base + k * 256;
        if (idx < n) pre[idx] += add;
    }
}

// ---------------- single-pass atomic-free fill using stored ranks -----------
__global__ __launch_bounds__(256)
void fill_kernel(const int* __restrict__ src, const int* __restrict__ dst,
                 const unsigned char* __restrict__ rank8,
                 const int* __restrict__ row_ptr, const unsigned char* __restrict__ offb,
                 int* __restrict__ col, int E) {
    int e = blockIdx.x * 256 + threadIdx.x;
    if (e >= E) return;
    int d = dst[e];
    int g = e / HCHUNK;
    int pos = row_ptr[d] + (int)offb[(size_t)g * NNODES + d] + (int)rank8[e];
    col[pos] = src[e];
}

// ---------------- weight prep: W1 transpose+perm, b1 perm, v2 = W2@Wfc, c0 --
__global__ __launch_bounds__(256)
void prep_w_kernel(const float* __restrict__ W1, const float* __restrict__ b1,
                   _Float16* __restrict__ Wt1, float* __restrict__ b1p,
                   const float* __restrict__ W2, const float* __restrict__ Wfc,
                   const float* __restrict__ b2, const float* __restrict__ bfc,
                   float* __restrict__ v2p, float* __restrict__ c0) {
    int b = blockIdx.x, t = threadIdx.x;
    if (b < WPREP_BLOCKS) {
        int id = b * 256 + t;
        if (id < NF * NH) {                    // W1 -> Wt1[n][perm(k)] f16
            int k = id >> 7, n = id & 127;
            Wt1[(size_t)n * NF + (k & ~15) + pos16(k & 15)] = (_Float16)W1[id];
        } else if (id < NF * NH + NH) {
            int pos = id - NF * NH;
            int k = (pos & ~15) + ipos16(pos & 15);
            b1p[pos] = b1[k];
        }
    } else {
        // v2 = W2 @ Wfc (perm order), c0 = b2.Wfc + bfc
        if (t < 128) {
            float s = 0.f;
            #pragma unroll 16
            for (int j = 0; j < 128; ++j) s += W2[t * 128 + j] * Wfc[j];
            v2p[(t & ~15) + pos16(t & 15)] = s;
        } else if (t < 192) {
            int lane = t - 128;
            float c = b2[lane] * Wfc[lane] + b2[lane + 64] * Wfc[lane + 64];
            #pragma unroll
            for (int off = 32; off > 0; off >>= 1) c += __shfl_down(c, off);
            if (lane == 0) c0[0] = c + bfc[0];
        }
    }
}

// ---------------- fused GEMM1: C = (x @ W1) * ns ----------------------------
// Round-17 measured optimum: 64-row x 2-wave blocks (1563 blocks, 16 KB LDS,
// ~8 resident independent streams/CU), BK=32 double-buffer, counted vmcnt(4)
// + raw s_barrier (loads stay in flight across barriers), rows clamped so
// every wave issues exactly 4 DMAs (uniform vmcnt).
__global__ __launch_bounds__(128, 4)
void gemm1_kernel(const float* __restrict__ X, const _Float16* __restrict__ Wt,
                  const float* __restrict__ norm_s, _Float16* __restrict__ Cout,
                  int N) {
    __shared__ __align__(16) float As[2][64 * 32];    // 2 x 8 KB
    const int tid = threadIdx.x;
    const int l = tid & 63, w = tid >> 6;      // 2 waves; wc = w
    const int wc = w;
    const int row0 = blockIdx.x * 64;

    const _Float16* Bb = Wt + (size_t)(wc * 64 + (l & 31)) * NF + (l >> 5) * 8;
    const int ar = l & 31;                     // A rows ar, ar+32
    const int swz = ar & 7;                    // (ar+32)&7 == ar&7
    const int g = l >> 5;
    const int lr = l >> 3, lc = l & 7;         // staging: 8 rows/DMA, 8 chunks/row
    floatx16 acc[2][2] = {};

    // prologue: stage slab 0 into buf 0 (4 DMAs/wave, rows clamped)
    #pragma unroll
    for (int i = 0; i < 4; ++i) {
        int R = w * 32 + i * 8;
        int r = R + lr;
        int grow = min(row0 + r, N - 1);
        int srcc = lc ^ (r & 7);
        load_lds16(X + (size_t)grow * NF + srcc * 4, &As[0][R * 32]);
    }

    for (int t = 0; t < 8; ++t) {
        const int cur = t & 1;
        if (t < 7) {
            #pragma unroll
            for (int i = 0; i < 4; ++i) {
                int R = w * 32 + i * 8;
                int r = R + lr;
                int grow = min(row0 + r, N - 1);
                int srcc = lc ^ (r & 7);
                load_lds16(X + (size_t)grow * NF + (t + 1) * 32 + srcc * 4,
                           &As[cur ^ 1][R * 32]);
            }
            __builtin_amdgcn_sched_barrier(0);
            asm volatile("s_waitcnt vmcnt(4)" ::: "memory");   // slab t done; t+1 in flight
            __builtin_amdgcn_sched_barrier(0);
        } else {
            __builtin_amdgcn_sched_barrier(0);
            asm volatile("s_waitcnt vmcnt(0)" ::: "memory");
            __builtin_amdgcn_sched_barrier(0);
        }
        __builtin_amdgcn_s_barrier();          // raw: no implicit vmcnt(0) drain
        #pragma unroll
        for (int kk = 0; kk < 2; ++kk) {
            int ca = kk * 4 + g;               // chunk with k = 16kk+4g+0..3
            int cb = ca + 2;                   // chunk with k = 16kk+4g+8..11
            float4 a0l = *(const float4*)&As[cur][(size_t)ar * 32 + (ca ^ swz) * 4];
            float4 a0h = *(const float4*)&As[cur][(size_t)ar * 32 + (cb ^ swz) * 4];
            float4 a1l = *(const float4*)&As[cur][(size_t)(ar + 32) * 32 + (ca ^ swz) * 4];
            float4 a1h = *(const float4*)&As[cur][(size_t)(ar + 32) * 32 + (cb ^ swz) * 4];
            half8v a0 = { (_Float16)a0l.x, (_Float16)a0l.y, (_Float16)a0l.z, (_Float16)a0l.w,
                          (_Float16)a0h.x, (_Float16)a0h.y, (_Float16)a0h.z, (_Float16)a0h.w };
            half8v a1 = { (_Float16)a1l.x, (_Float16)a1l.y, (_Float16)a1l.z, (_Float16)a1l.w,
                          (_Float16)a1h.x, (_Float16)a1h.y, (_Float16)a1h.z, (_Float16)a1h.w };
            const _Float16* bp = Bb + (t * 2 + kk) * 16;
            half8v b0 = *(const half8v*)bp;
            half8v b1 = *(const half8v*)(bp + (size_t)32 * NF);
            acc[0][0] = __builtin_amdgcn_mfma_f32_32x32x16_f16(a0, b0, acc[0][0], 0, 0, 0);
            acc[0][1] = __builtin_amdgcn_mfma_f32_32x32x16_f16(a0, b1, acc[0][1], 0, 0, 0);
            acc[1][0] = __builtin_amdgcn_mfma_f32_32x32x16_f16(a1, b0, acc[1][0], 0, 0, 0);
            acc[1][1] = __builtin_amdgcn_mfma_f32_32x32x16_f16(a1, b1, acc[1][1], 0, 0, 0);
        }
        __builtin_amdgcn_s_barrier();          // all reads of As[cur] done before t+2 stage
    }

    // epilogue: D row = (r&3)+8*(r>>2)+4*(l>>5), col = l&31; scale by ns[row]
    const int cpos = pos16(l & 15);
    const int chi = ((l >> 4) & 1) << 4;
    #pragma unroll
    for (int m = 0; m < 2; ++m) {
        #pragma unroll
        for (int r = 0; r < 16; ++r) {
            int rloc = m * 32 + (r & 3) + ((r >> 2) << 3) + ((l >> 5) << 2);
            int grow = row0 + rloc;
            if (grow < N) {
                float s = norm_s[grow];
                #pragma unroll
                for (int n = 0; n < 2; ++n) {
                    int colbase = wc * 64 + n * 32 + chi;
                    Cout[(size_t)grow * NH + colbase + cpos] = (_Float16)(acc[m][n][r] * s);
                }
            }
        }
    }
}

// ---------------- fused gather + layer-1 epilogue + z-dot, one wave/node ----
__global__ __launch_bounds__(512)
void gatherz_kernel(const _Float16* __restrict__ m, const int* __restrict__ row_ptr,
                    const int* __restrict__ col, const float* __restrict__ norm_d,
                    const float* __restrict__ norm_s, const float* __restrict__ b1p,
                    const float* __restrict__ v2p, float* __restrict__ z, int N) {
    int w = (blockIdx.x * 512 + threadIdx.x) >> 6;
    int lane = threadIdx.x & 63;
    if (w >= N) return;
    int beg = __builtin_amdgcn_readfirstlane(row_ptr[w]);
    int end = __builtin_amdgcn_readfirstlane(row_ptr[w + 1]);
    const unsigned* mu = (const unsigned*)m + lane;  // lane's column slot
    float ax = 0.f, ay = 0.f;
    int i = beg;
    for (; i + 15 < end; i += 16) {
        unsigned u[16];
        #pragma unroll
        for (int j = 0; j < 16; ++j) u[j] = mu[(size_t)col[i + j] * 64];
        #pragma unroll
        for (int j = 0; j < 16; ++j) { float2 v = h2f2(u[j]); ax += v.x; ay += v.y; }
    }
    for (; i + 3 < end; i += 4) {
        unsigned u[4];
        #pragma unroll
        for (int j = 0; j < 4; ++j) u[j] = mu[(size_t)col[i + j] * 64];
        #pragma unroll
        for (int j = 0; j < 4; ++j) { float2 v = h2f2(u[j]); ax += v.x; ay += v.y; }
    }
    for (; i < end; ++i) {
        float2 v = h2f2(mu[(size_t)col[i] * 64]);
        ax += v.x; ay += v.y;
    }
    float nd = norm_d[w], ns = norm_s[w];
    float2 bv = ((const float2*)b1p)[lane];
    float hx = fmaxf(fmaf(ax, nd, bv.x), 0.f) * ns;
    float hy = fmaxf(fmaf(ay, nd, bv.y), 0.f) * ns;
    float2 w2 = ((const float2*)v2p)[lane];
    float p = fmaf(hx, w2.x, hy * w2.y);
    #pragma unroll
    for (int off = 32; off > 0; off >>= 1) p += __shfl_down(p, off);
    if (lane == 0) z[w] = p;
}

// ---------------- scalar CSR sum: out[w] = nd*sum z[col] + c0 ---------------
__global__ __launch_bounds__(256)
void outsum_kernel(const float* __restrict__ z, const int* __restrict__ row_ptr,
                   const int* __restrict__ col, const float* __restrict__ norm_d,
                   const float* __restrict__ c0, float* __restrict__ out, int N) {
    int w = blockIdx.x * 256 + threadIdx.x;
    if (w >= N) return;
    int beg = row_ptr[w], end = row_ptr[w + 1];
    float s0 = 0.f, s1 = 0.f, s2 = 0.f, s3 = 0.f;
    int i = beg;
    for (; i + 3 < end; i += 4) {
        s0 += z[col[i]];     s1 += z[col[i + 1]];
        s2 += z[col[i + 2]]; s3 += z[col[i + 3]];
    }
    for (; i < end; ++i) s0 += z[col[i]];
    out[w] = norm_d[w] * ((s0 + s1) + (s2 + s3)) + c0[0];
}

extern "C" void kernel_launch(void* const* d_in, const int* in_sizes, int n_in,
                              void* d_out, int out_size, void* d_ws, size_t ws_size,
                              hipStream_t stream) {
    const float* x   = (const float*)d_in[0];
    const float* W1  = (const float*)d_in[1];
    const float* b1  = (const float*)d_in[2];
    const float* W2  = (const float*)d_in[3];
    const float* b2  = (const float*)d_in[4];
    const float* Wfc = (const float*)d_in[5];
    const float* bfc = (const float*)d_in[6];
    const int*   src = (const int*)d_in[7];
    const int*   dst = (const int*)d_in[8];
    float* out = (float*)d_out;

    const int N = NNODES, E = NEDGES;

    // workspace layout (all offsets 16B-aligned)
    char* p = (char*)d_ws;
    float*    norm_s = (float*)p;      p += (size_t)N * 4;
    float*    norm_d = (float*)p;      p += (size_t)N * 4;
    _Float16* bufA_h = (_Float16*)p;   p += (size_t)N * NH * 2;   // m1 (25.6 MB)
    _Float16* Wt1    = (_Float16*)p;   p += (size_t)NF * NH * 2;
    float*    b1p    = (float*)p;      p += NH * 4;
    float*    v2p    = (float*)p;      p += NH * 4;
    float*    c0     = (float*)p;      p += 16;
    float*    z      = (float*)p;      p += (size_t)N * 4;
    int*      cnt_in = (int*)p;        p += (size_t)N * 4;
    int*      row_ptr= (int*)p;        p += (size_t)(N + 1) * 4 + 12;  // keep 16B align
    int*      col    = (int*)p;        p += (size_t)E * 4;
    int*      bsum   = (int*)p;        p += 128 * 4;
    unsigned char* rank8 = (unsigned char*)p;  p += (size_t)E;    // 1.6 MB
    unsigned* partial= (unsigned*)p;   // HG * HWORDS * 4 = 40 MB
    // offb (20 MB) aliases bufA_h (25.6 MB): dead before gemm1 writes bufA_h.
    unsigned char* offb = (unsigned char*)bufA_h;

    // ---- CSR build + norms + weight prep (zero global atomics) ----
    hist_part_kernel<<<HG, 512, 0, stream>>>(src, dst, partial, rank8);
    degscan_kernel<<<(HWORDS + 255) / 256, 256, 0, stream>>>(partial, offb, norm_s, norm_d, cnt_in);
    scanA_kernel<<<SCAN_NBLK, 256, 0, stream>>>(cnt_in, row_ptr, bsum, N);
    scanB_kernel<<<1, 128, 0, stream>>>(bsum, SCAN_NBLK, row_ptr);
    scanC_kernel<<<SCAN_NBLK, 256, 0, stream>>>(row_ptr, bsum, N);
    fill_kernel<<<(E + 255) / 256, 256, 0, stream>>>(src, dst, rank8, row_ptr, offb, col, E);
    prep_w_kernel<<<WPREP_BLOCKS + 1, 256, 0, stream>>>(W1, b1, Wt1, b1p,
                                                        W2, Wfc, b2, bfc, v2p, c0);

    // ---- layer 1 GEMM (convx fused, 64-row 2-wave dbuf): m1 = (x @ W1) * ns ----
    gemm1_kernel<<<(N + 63) / 64, 128, 0, stream>>>(x, Wt1, norm_s, bufA_h, N);
    // ---- fused: agg1 -> h -> z (layer 2 collapsed into v2 dot) ----
    gatherz_kernel<<<((size_t)N * 64 + 511) / 512, 512, 0, stream>>>(
        bufA_h, row_ptr, col, norm_d, norm_s, b1p, v2p, z, N);
    // ---- out[w] = nd * sum z[col] + c0 ----
    outsum_kernel<<<(N + 255) / 256, 256, 0, stream>>>(z, row_ptr, col, norm_d, c0, out, N);
}